// Round 1
// baseline (1774.870 us; speedup 1.0000x reference)
//
#include <hip/hip_runtime.h>
#include <math.h>

// Problem constants (from reference)
#define NN 20000
#define NE 320000
#define FD 128
#define RBFN 20
#define RC_ 5.0f
#define NITER 3
#define NMOL 64
#define F3 (3*FD)   // 384
#define F2 (2*FD)   // 256
#define PI_ 3.14159265358979323846f

// ---------------------------------------------------------------- elementwise
__global__ __launch_bounds__(256) void embed_kernel(const int* __restrict__ z,
    const float* __restrict__ emb, float* __restrict__ s)
{
    int idx = blockIdx.x * 256 + threadIdx.x;
    if (idx >= NN * FD) return;
    int n = idx >> 7, f = idx & 127;
    s[idx] = emb[z[n] * FD + f];
}

__global__ __launch_bounds__(256) void zero_f_kernel(float* __restrict__ p, int n)
{
    int idx = blockIdx.x * 256 + threadIdx.x;
    if (idx < n) p[idx] = 0.f;
}

__global__ __launch_bounds__(256) void zero_i_kernel(int* __restrict__ p, int n)
{
    int idx = blockIdx.x * 256 + threadIdx.x;
    if (idx < n) p[idx] = 0;
}

// rbf/cut are loop-invariant: precompute once per launch
__global__ __launch_bounds__(256) void rbf_kernel(const float* __restrict__ dist,
    float* __restrict__ rbf, float* __restrict__ cutb)
{
    int e = blockIdx.x * 256 + threadIdx.x;
    if (e >= NE) return;
    float d = dist[e];
    float inv = 1.f / d;
    float base = PI_ * d / RC_;
    #pragma unroll
    for (int k = 0; k < RBFN; k++)
        rbf[e * RBFN + k] = sinf((float)(k + 1) * base) * inv;
    cutb[e] = 0.5f * (cosf(base) + 1.f) * (d < RC_ ? 1.f : 0.f);
}

// ---------------------------------------------------------------- CSR build
__global__ __launch_bounds__(256) void csr_count_kernel(const int* __restrict__ graph,
    int* __restrict__ cnt)
{
    int e = blockIdx.x * 256 + threadIdx.x;
    if (e >= NE) return;
    atomicAdd(&cnt[graph[2 * e]], 1);
}

__global__ __launch_bounds__(1024) void csr_scan_kernel(const int* __restrict__ cnt,
    int* __restrict__ row_ptr, int* __restrict__ cursor)
{
    __shared__ int sd[1024];
    int tid = threadIdx.x;
    const int chunk = (NN + 1023) / 1024;   // 20
    int start = tid * chunk;
    int end = start + chunk; if (end > NN) end = NN;
    int sum = 0;
    for (int j = start; j < end; j++) sum += cnt[j];
    sd[tid] = sum;
    __syncthreads();
    for (int off = 1; off < 1024; off <<= 1) {
        int v = 0;
        if (tid >= off) v = sd[tid - off];
        __syncthreads();
        if (tid >= off) sd[tid] += v;
        __syncthreads();
    }
    int run = (tid == 0) ? 0 : sd[tid - 1];
    for (int j = start; j < end; j++) {
        row_ptr[j] = run;
        cursor[j]  = run;
        run += cnt[j];
    }
    if (tid == 0) row_ptr[NN] = NE;
}

__global__ __launch_bounds__(256) void csr_scatter_kernel(const int* __restrict__ graph,
    int* __restrict__ cursor, int* __restrict__ edge_list)
{
    int e = blockIdx.x * 256 + threadIdx.x;
    if (e >= NE) return;
    int p = atomicAdd(&cursor[graph[2 * e]], 1);
    edge_list[p] = e;
}

// ---------------------------------------------------------------- fp32 GEMM
// C[m][n] = act( sum_k A[m*K+k]*Wt[n*K+k] + bias[n] )   (Wt is (Nc,K) row-major)
// BM=64, BN=64, BK=32, 256 threads, 4x4 per thread.
template<bool SILU>
__global__ __launch_bounds__(256) void gemm_tn(const float* __restrict__ A,
    const float* __restrict__ Wt, const float* __restrict__ bias,
    float* __restrict__ C, int M, int K, int Nc)
{
    __shared__ float As[32][65];
    __shared__ float Bs[32][65];
    int bm = blockIdx.x * 64;
    int bn = blockIdx.y * 64;
    int tid = threadIdx.x;
    int tx = tid & 15, ty = tid >> 4;
    int lrow = tid >> 2;          // 0..63
    int lcol = (tid & 3) * 8;     // 0,8,16,24
    float acc[4][4] = {};
    for (int k0 = 0; k0 < K; k0 += 32) {
        // A tile
        {
            int gm = bm + lrow;
            if (gm < M) {
                const float* ap = A + (size_t)gm * K + k0 + lcol;
                float4 u0 = *(const float4*)ap;
                float4 u1 = *(const float4*)(ap + 4);
                As[lcol+0][lrow]=u0.x; As[lcol+1][lrow]=u0.y; As[lcol+2][lrow]=u0.z; As[lcol+3][lrow]=u0.w;
                As[lcol+4][lrow]=u1.x; As[lcol+5][lrow]=u1.y; As[lcol+6][lrow]=u1.z; As[lcol+7][lrow]=u1.w;
            } else {
                #pragma unroll
                for (int j = 0; j < 8; j++) As[lcol+j][lrow] = 0.f;
            }
        }
        // W tile (Nc is always a multiple of 64 -> no guard)
        {
            int gn = bn + lrow;
            const float* wp = Wt + (size_t)gn * K + k0 + lcol;
            float4 w0 = *(const float4*)wp;
            float4 w1 = *(const float4*)(wp + 4);
            Bs[lcol+0][lrow]=w0.x; Bs[lcol+1][lrow]=w0.y; Bs[lcol+2][lrow]=w0.z; Bs[lcol+3][lrow]=w0.w;
            Bs[lcol+4][lrow]=w1.x; Bs[lcol+5][lrow]=w1.y; Bs[lcol+6][lrow]=w1.z; Bs[lcol+7][lrow]=w1.w;
        }
        __syncthreads();
        #pragma unroll
        for (int k = 0; k < 32; k++) {
            float af[4], bf[4];
            #pragma unroll
            for (int i = 0; i < 4; i++) af[i] = As[k][ty * 4 + i];
            #pragma unroll
            for (int j = 0; j < 4; j++) bf[j] = Bs[k][tx * 4 + j];
            #pragma unroll
            for (int i = 0; i < 4; i++)
                #pragma unroll
                for (int j = 0; j < 4; j++)
                    acc[i][j] += af[i] * bf[j];
        }
        __syncthreads();
    }
    #pragma unroll
    for (int i = 0; i < 4; i++) {
        int gm = bm + ty * 4 + i;
        if (gm >= M) continue;
        #pragma unroll
        for (int j = 0; j < 4; j++) {
            int gn = bn + tx * 4 + j;
            float v = acc[i][j] + (bias ? bias[gn] : 0.f);
            if (SILU) v = v / (1.f + __expf(-v));
            C[(size_t)gm * Nc + gn] = v;
        }
    }
}

// ---------------------------------------------------------------- edge aggregate
// One block (128 threads) per node n. Thread f handles feature f.
// s_out[n] = s_in[n] + 2*sum_e rs ; v_out[n][c] = v_in[n][c] + 2*sum_e (v_in[dst][c]*rv + sense[c]*rd)
__global__ __launch_bounds__(128) void edge_aggregate_kernel(
    const int* __restrict__ graph, const float* __restrict__ sense,
    const float* __restrict__ rbf, const float* __restrict__ cutb,
    const float* __restrict__ ew, const float* __restrict__ eb,
    const float* __restrict__ a, const float* __restrict__ s_in,
    const float* __restrict__ v_in,
    const int* __restrict__ row_ptr, const int* __restrict__ edge_list,
    float* __restrict__ s_out, float* __restrict__ v_out)
{
    int n = blockIdx.x;
    int f = threadIdx.x;
    // preload ew rows f, F+f, 2F+f into registers (60 VGPRs) + biases
    float ewv[RBFN], ews[RBFN], ewd[RBFN];
    const float* e0 = ew + (size_t)f * RBFN;
    const float* e1 = ew + (size_t)(FD + f) * RBFN;
    const float* e2 = ew + (size_t)(2 * FD + f) * RBFN;
    #pragma unroll
    for (int k = 0; k < RBFN; k++) { ewv[k] = e0[k]; ews[k] = e1[k]; ewd[k] = e2[k]; }
    float ebv = eb[f], ebs = eb[FD + f], ebd = eb[2 * FD + f];

    float accs = 0.f, accv0 = 0.f, accv1 = 0.f, accv2 = 0.f;
    int beg = row_ptr[n], end = row_ptr[n + 1];
    for (int j = beg; j < end; j++) {
        int e = edge_list[j];
        int dst = graph[2 * e + 1];
        float ce = cutb[e];
        const float* rb = rbf + (size_t)e * RBFN;
        float drv = ebv, drs = ebs, drd = ebd;
        #pragma unroll
        for (int k = 0; k < RBFN; k++) {
            float r = rb[k];
            drv += r * ewv[k]; drs += r * ews[k]; drd += r * ewd[k];
        }
        drv *= ce; drs *= ce; drd *= ce;
        const float* arow = a + (size_t)dst * F3;
        float rv = arow[f]          * drv;
        float rs = arow[FD + f]     * drs;
        float rd = arow[2 * FD + f] * drd;
        accs += rs;
        const float* vrow = v_in + (size_t)dst * F3;
        float sx = sense[3 * e + 0], sy = sense[3 * e + 1], sz = sense[3 * e + 2];
        accv0 += vrow[f]           * rv + sx * rd;
        accv1 += vrow[FD + f]      * rv + sy * rd;
        accv2 += vrow[2 * FD + f]  * rv + sz * rd;
    }
    int nb = n * FD + f;
    s_out[nb] = s_in[nb] + 2.f * accs;
    int vb = n * F3 + f;
    v_out[vb]          = v_in[vb]          + 2.f * accv0;
    v_out[vb + FD]     = v_in[vb + FD]     + 2.f * accv1;
    v_out[vb + 2 * FD] = v_in[vb + 2 * FD] + 2.f * accv2;
}

// ---------------------------------------------------------------- h build: [s, |Vv|]
__global__ __launch_bounds__(256) void build_h_kernel(const float* __restrict__ s_mid,
    const float* __restrict__ Vv, float* __restrict__ h)
{
    int idx = blockIdx.x * 256 + threadIdx.x;
    if (idx >= NN * FD) return;
    int n = idx >> 7, f = idx & 127;
    h[n * F2 + f] = s_mid[idx];
    float x0 = Vv[n * F3 + f];
    float x1 = Vv[n * F3 + FD + f];
    float x2 = Vv[n * F3 + 2 * FD + f];
    h[n * F2 + FD + f] = sqrtf(x0 * x0 + x1 * x1 + x2 * x2);
}

// ---------------------------------------------------------------- node update
__global__ __launch_bounds__(256) void update_kernel(const float* __restrict__ s_mid,
    const float* __restrict__ v_mid, const float* __restrict__ a2,
    const float* __restrict__ Uv, const float* __restrict__ Vv,
    float* __restrict__ s_out, float* __restrict__ v_out)
{
    int idx = blockIdx.x * 256 + threadIdx.x;
    if (idx >= NN * FD) return;
    int n = idx >> 7, f = idx & 127;
    int vb = n * F3 + f;
    float u0 = Uv[vb], u1 = Uv[vb + FD], u2 = Uv[vb + 2 * FD];
    float w0 = Vv[vb], w1 = Vv[vb + FD], w2 = Vv[vb + 2 * FD];
    float dot = u0 * w0 + u1 * w1 + u2 * w2;
    float avv = a2[n * F3 + f];
    float asv = a2[n * F3 + FD + f];
    float ass = a2[n * F3 + 2 * FD + f];
    s_out[idx] = s_mid[idx] + ass + asv * dot;
    v_out[vb]          = v_mid[vb]          + avv * u0;
    v_out[vb + FD]     = v_mid[vb + FD]     + avv * u1;
    v_out[vb + 2 * FD] = v_mid[vb + 2 * FD] + avv * u2;
}

// ---------------------------------------------------------------- final head + molecule reduce
__global__ __launch_bounds__(64) void zero_out_kernel(float* __restrict__ out)
{
    if (threadIdx.x < NMOL) out[threadIdx.x] = 0.f;
}

__global__ __launch_bounds__(256) void final_reduce_kernel(const float* __restrict__ t,
    const float* __restrict__ ow2, const float* __restrict__ ob2,
    const int* __restrict__ gidx, float* __restrict__ out)
{
    int gt = blockIdx.x * 256 + threadIdx.x;
    int n = gt >> 6;
    int lane = threadIdx.x & 63;
    if (n >= NN) return;
    float v = t[n * FD + lane] * ow2[lane] + t[n * FD + 64 + lane] * ow2[64 + lane];
    #pragma unroll
    for (int off = 32; off > 0; off >>= 1) v += __shfl_down(v, off);
    if (lane == 0) atomicAdd(&out[gidx[n]], v + ob2[0]);
}

// ---------------------------------------------------------------- launch
extern "C" void kernel_launch(void* const* d_in, const int* in_sizes, int n_in,
                              void* d_out, int out_size, void* d_ws, size_t ws_size,
                              hipStream_t stream)
{
    const int*   z     = (const int*)d_in[0];
    const int*   graph = (const int*)d_in[1];
    const float* dist  = (const float*)d_in[2];
    const float* sense = (const float*)d_in[3];
    const int*   gidx  = (const int*)d_in[4];
    const float* emb   = (const float*)d_in[5];
    const float* mw1   = (const float*)d_in[6];
    const float* mb1   = (const float*)d_in[7];
    const float* mw2   = (const float*)d_in[8];
    const float* mb2   = (const float*)d_in[9];
    const float* ew    = (const float*)d_in[10];
    const float* eb    = (const float*)d_in[11];
    const float* uw    = (const float*)d_in[12];
    const float* vw    = (const float*)d_in[13];
    const float* aw1   = (const float*)d_in[14];
    const float* ab1   = (const float*)d_in[15];
    const float* aw2   = (const float*)d_in[16];
    const float* ab2   = (const float*)d_in[17];
    const float* ow1   = (const float*)d_in[18];
    const float* ob1   = (const float*)d_in[19];
    const float* ow2   = (const float*)d_in[20];
    const float* ob2   = (const float*)d_in[21];
    float* out = (float*)d_out;

    // workspace carve-up (~244 MB total)
    float* W = (float*)d_ws;
    float* s_a    = W; W += (size_t)NN * FD;
    float* s_b    = W; W += (size_t)NN * FD;
    float* v_a    = W; W += (size_t)NN * F3;
    float* v_b    = W; W += (size_t)NN * F3;
    float* a_buf  = W; W += (size_t)NN * F3;   // aliased as h later in the iteration
    float* t_buf  = W; W += (size_t)NN * FD;
    float* a2_buf = W; W += (size_t)NN * F3;
    float* Uv     = W; W += (size_t)NN * F3;
    float* Vv     = W; W += (size_t)NN * F3;
    float* rbf    = W; W += (size_t)NE * RBFN;
    float* cutb   = W; W += (size_t)NE;
    int* ip = (int*)W;
    int* row_ptr   = ip; ip += NN + 1;
    int* cnt       = ip; ip += NN;
    int* cursor    = ip; ip += NN;
    int* edge_list = ip; ip += NE;
    float* h_buf = a_buf;

    const int TB = 256;
    dim3 b256(TB);

    // --- precompute ---
    embed_kernel<<<dim3((NN * FD + TB - 1) / TB), b256, 0, stream>>>(z, emb, s_a);
    zero_f_kernel<<<dim3((NN * F3 + TB - 1) / TB), b256, 0, stream>>>(v_a, NN * F3);
    rbf_kernel<<<dim3((NE + TB - 1) / TB), b256, 0, stream>>>(dist, rbf, cutb);
    zero_i_kernel<<<dim3((NN + TB - 1) / TB), b256, 0, stream>>>(cnt, NN);
    csr_count_kernel<<<dim3((NE + TB - 1) / TB), b256, 0, stream>>>(graph, cnt);
    csr_scan_kernel<<<dim3(1), dim3(1024), 0, stream>>>(cnt, row_ptr, cursor);
    csr_scatter_kernel<<<dim3((NE + TB - 1) / TB), b256, 0, stream>>>(graph, cursor, edge_list);

    dim3 gN2((NN + 63) / 64, FD / 64);     // M=N, Nc=128
    dim3 gN6((NN + 63) / 64, F3 / 64);     // M=N, Nc=384
    dim3 gV2((3 * NN + 63) / 64, FD / 64); // M=3N, Nc=128

    for (int i = 0; i < NITER; i++) {
        // a = silu(s@mw1^T+mb1)@mw2^T+mb2
        gemm_tn<true ><<<gN2, b256, 0, stream>>>(s_a, mw1 + (size_t)i * FD * FD, mb1 + (size_t)i * FD, t_buf, NN, FD, FD);
        gemm_tn<false><<<gN6, b256, 0, stream>>>(t_buf, mw2 + (size_t)i * F3 * FD, mb2 + (size_t)i * F3, a_buf, NN, FD, F3);
        // message passing: s_b = s_a + 2*segsum(rs), v_b = v_a + 2*segsum(resv)
        edge_aggregate_kernel<<<dim3(NN), dim3(128), 0, stream>>>(
            graph, sense, rbf, cutb,
            ew + (size_t)i * F3 * RBFN, eb + (size_t)i * F3,
            a_buf, s_a, v_a, row_ptr, edge_list, s_b, v_b);
        // Uv, Vv
        gemm_tn<false><<<gV2, b256, 0, stream>>>(v_b, uw + (size_t)i * FD * FD, nullptr, Uv, 3 * NN, FD, FD);
        gemm_tn<false><<<gV2, b256, 0, stream>>>(v_b, vw + (size_t)i * FD * FD, nullptr, Vv, 3 * NN, FD, FD);
        // h = [s_b, |Vv|]
        build_h_kernel<<<dim3((NN * FD + TB - 1) / TB), b256, 0, stream>>>(s_b, Vv, h_buf);
        // a2 = silu(h@aw1^T+ab1)@aw2^T+ab2
        gemm_tn<true ><<<gN2, b256, 0, stream>>>(h_buf, aw1 + (size_t)i * FD * F2, ab1 + (size_t)i * FD, t_buf, NN, F2, FD);
        gemm_tn<false><<<gN6, b256, 0, stream>>>(t_buf, aw2 + (size_t)i * F3 * FD, ab2 + (size_t)i * F3, a2_buf, NN, FD, F3);
        // s_a, v_a <- updated state
        update_kernel<<<dim3((NN * FD + TB - 1) / TB), b256, 0, stream>>>(s_b, v_b, a2_buf, Uv, Vv, s_a, v_a);
    }

    // output head + molecule segment-sum
    gemm_tn<true><<<gN2, b256, 0, stream>>>(s_a, ow1, ob1, t_buf, NN, FD, FD);
    zero_out_kernel<<<dim3(1), dim3(64), 0, stream>>>(out);
    final_reduce_kernel<<<dim3((NN * 64 + TB - 1) / TB), b256, 0, stream>>>(t_buf, ow2, ob2, gidx, out);
}

// Round 2
// 1422.406 us; speedup vs baseline: 1.2478x; 1.2478x over previous
//
#include <hip/hip_runtime.h>
#include <math.h>

// Problem constants (from reference)
#define NN 20000
#define NE 320000
#define FD 128
#define RBFN 20
#define RC_ 5.0f
#define NITER 3
#define NMOL 64
#define F3 (3*FD)   // 384
#define F2 (2*FD)   // 256
#define PI_ 3.14159265358979323846f

typedef __attribute__((ext_vector_type(8))) short  bf16x8;
typedef __attribute__((ext_vector_type(4))) float  floatx4;
typedef __attribute__((ext_vector_type(4))) unsigned short ushortx4;

__device__ __forceinline__ unsigned short f2b(float x) {
    union { float f; unsigned int u; } v; v.f = x;
    unsigned int u = v.u;
    return (unsigned short)((u + 0x7fffu + ((u >> 16) & 1u)) >> 16);   // RNE
}

// ---------------------------------------------------------------- elementwise
__global__ __launch_bounds__(256) void embed_kernel(const int* __restrict__ z,
    const float* __restrict__ emb, float* __restrict__ s)
{
    int idx = blockIdx.x * 256 + threadIdx.x;
    if (idx >= NN * FD) return;
    int n = idx >> 7, f = idx & 127;
    s[idx] = emb[z[n] * FD + f];
}

__global__ __launch_bounds__(256) void zero_f_kernel(float* __restrict__ p, int n)
{
    int idx = blockIdx.x * 256 + threadIdx.x;
    if (idx < n) p[idx] = 0.f;
}

__global__ __launch_bounds__(256) void zero_i_kernel(int* __restrict__ p, int n)
{
    int idx = blockIdx.x * 256 + threadIdx.x;
    if (idx < n) p[idx] = 0;
}

// rbf/cut are loop-invariant: precompute once per launch
__global__ __launch_bounds__(256) void rbf_kernel(const float* __restrict__ dist,
    float* __restrict__ rbf, float* __restrict__ cutb)
{
    int e = blockIdx.x * 256 + threadIdx.x;
    if (e >= NE) return;
    float d = dist[e];
    float inv = 1.f / d;
    float base = PI_ * d / RC_;
    #pragma unroll
    for (int k = 0; k < RBFN; k++)
        rbf[e * RBFN + k] = sinf((float)(k + 1) * base) * inv;
    cutb[e] = 0.5f * (cosf(base) + 1.f) * (d < RC_ ? 1.f : 0.f);
}

// ---------------------------------------------------------------- CSR build
__global__ __launch_bounds__(256) void csr_count_kernel(const int* __restrict__ graph,
    int* __restrict__ cnt)
{
    int e = blockIdx.x * 256 + threadIdx.x;
    if (e >= NE) return;
    atomicAdd(&cnt[graph[2 * e]], 1);
}

__global__ __launch_bounds__(1024) void csr_scan_kernel(const int* __restrict__ cnt,
    int* __restrict__ row_ptr, int* __restrict__ cursor)
{
    __shared__ int sd[1024];
    int tid = threadIdx.x;
    const int chunk = (NN + 1023) / 1024;   // 20
    int start = tid * chunk;
    int end = start + chunk; if (end > NN) end = NN;
    int sum = 0;
    for (int j = start; j < end; j++) sum += cnt[j];
    sd[tid] = sum;
    __syncthreads();
    for (int off = 1; off < 1024; off <<= 1) {
        int v = 0;
        if (tid >= off) v = sd[tid - off];
        __syncthreads();
        if (tid >= off) sd[tid] += v;
        __syncthreads();
    }
    int run = (tid == 0) ? 0 : sd[tid - 1];
    for (int j = start; j < end; j++) {
        row_ptr[j] = run;
        cursor[j]  = run;
        run += cnt[j];
    }
    if (tid == 0) row_ptr[NN] = NE;
}

__global__ __launch_bounds__(256) void csr_scatter_kernel(const int* __restrict__ graph,
    int* __restrict__ cursor, int* __restrict__ edge_list)
{
    int e = blockIdx.x * 256 + threadIdx.x;
    if (e >= NE) return;
    int p = atomicAdd(&cursor[graph[2 * e]], 1);
    edge_list[p] = e;
}

// ---------------------------------------------------------------- bf16 MFMA GEMM
// C[m][n] = act( sum_k A[m*K+k]*Wt[n*K+k] + bias[n] ),  Wt is (Nc,K) row-major.
// fp32 inputs converted RNE->bf16 during LDS staging; fp32 accumulate.
// Block: 256 threads (4 waves), tile 64x64. Wave w: rows (w>>1)*32, cols (w&1)*32,
// as 2x2 of 16x16x32 MFMA tiles. K staged in 128-wide chunks (K must be mult of 128).
#define KB 128
#define LPAD 8
template<bool SILU>
__global__ __launch_bounds__(256) void gemm_mfma(const float* __restrict__ A,
    const float* __restrict__ Wt, const float* __restrict__ bias,
    float* __restrict__ C, int M, int K, int Nc)
{
    __shared__ unsigned short As[64][KB + LPAD];
    __shared__ unsigned short Bs[64][KB + LPAD];
    const int bm = blockIdx.x * 64;
    const int bn = blockIdx.y * 64;
    const int tid = threadIdx.x;
    const int r = tid >> 2;       // 0..63 staging row
    const int q = tid & 3;        // quarter of KB (32 floats)
    const int wave = tid >> 6;
    const int lane = tid & 63;
    const int wm = (wave >> 1) * 32;
    const int wn = (wave & 1) * 32;
    const int quad = lane >> 4;
    const int lr = lane & 15;

    floatx4 acc[2][2];
    #pragma unroll
    for (int i = 0; i < 2; i++)
        #pragma unroll
        for (int j = 0; j < 2; j++)
            acc[i][j] = (floatx4)0.f;

    for (int ko = 0; ko < K; ko += KB) {
        // stage A chunk (rows bm..bm+63, cols ko..ko+127) as bf16
        {
            int gm = bm + r;
            unsigned short* dA = &As[r][q * 32];
            if (gm < M) {
                const float* ap = A + (size_t)gm * K + ko + q * 32;
                #pragma unroll
                for (int x = 0; x < 32; x += 4) {
                    float4 u = *(const float4*)(ap + x);
                    ushortx4 p;
                    p.x = f2b(u.x); p.y = f2b(u.y); p.z = f2b(u.z); p.w = f2b(u.w);
                    *(ushortx4*)&dA[x] = p;
                }
            } else {
                #pragma unroll
                for (int x = 0; x < 32; x += 4)
                    *(ushortx4*)&dA[x] = (ushortx4)0;
            }
        }
        // stage B chunk (Wt rows bn..bn+63) — Nc is a multiple of 64, no guard
        {
            int gn = bn + r;
            const float* wp = Wt + (size_t)gn * K + ko + q * 32;
            unsigned short* dB = &Bs[r][q * 32];
            #pragma unroll
            for (int x = 0; x < 32; x += 4) {
                float4 u = *(const float4*)(wp + x);
                ushortx4 p;
                p.x = f2b(u.x); p.y = f2b(u.y); p.z = f2b(u.z); p.w = f2b(u.w);
                *(ushortx4*)&dB[x] = p;
            }
        }
        __syncthreads();
        #pragma unroll
        for (int kk = 0; kk < KB; kk += 32) {
            bf16x8 a0 = *(const bf16x8*)&As[wm + lr     ][kk + quad * 8];
            bf16x8 a1 = *(const bf16x8*)&As[wm + 16 + lr][kk + quad * 8];
            bf16x8 b0 = *(const bf16x8*)&Bs[wn + lr     ][kk + quad * 8];
            bf16x8 b1 = *(const bf16x8*)&Bs[wn + 16 + lr][kk + quad * 8];
            acc[0][0] = __builtin_amdgcn_mfma_f32_16x16x32_bf16(a0, b0, acc[0][0], 0, 0, 0);
            acc[0][1] = __builtin_amdgcn_mfma_f32_16x16x32_bf16(a0, b1, acc[0][1], 0, 0, 0);
            acc[1][0] = __builtin_amdgcn_mfma_f32_16x16x32_bf16(a1, b0, acc[1][0], 0, 0, 0);
            acc[1][1] = __builtin_amdgcn_mfma_f32_16x16x32_bf16(a1, b1, acc[1][1], 0, 0, 0);
        }
        __syncthreads();
    }

    // epilogue: C/D layout col=lane&15, row=quad*4+reg
    #pragma unroll
    for (int i = 0; i < 2; i++) {
        #pragma unroll
        for (int j = 0; j < 2; j++) {
            int gn = bn + wn + j * 16 + lr;
            float bb = bias ? bias[gn] : 0.f;
            #pragma unroll
            for (int rr = 0; rr < 4; rr++) {
                int gm = bm + wm + i * 16 + quad * 4 + rr;
                if (gm < M) {
                    float v = acc[i][j][rr] + bb;
                    if (SILU) v = v / (1.f + __expf(-v));
                    C[(size_t)gm * Nc + gn] = v;
                }
            }
        }
    }
}

// ---------------------------------------------------------------- edge aggregate
// One block (128 threads) per node n. Thread f handles feature f.
__global__ __launch_bounds__(128) void edge_aggregate_kernel(
    const int* __restrict__ graph, const float* __restrict__ sense,
    const float* __restrict__ rbf, const float* __restrict__ cutb,
    const float* __restrict__ ew, const float* __restrict__ eb,
    const float* __restrict__ a, const float* __restrict__ s_in,
    const float* __restrict__ v_in,
    const int* __restrict__ row_ptr, const int* __restrict__ edge_list,
    float* __restrict__ s_out, float* __restrict__ v_out)
{
    int n = blockIdx.x;
    int f = threadIdx.x;
    float ewv[RBFN], ews[RBFN], ewd[RBFN];
    const float* e0 = ew + (size_t)f * RBFN;
    const float* e1 = ew + (size_t)(FD + f) * RBFN;
    const float* e2 = ew + (size_t)(2 * FD + f) * RBFN;
    #pragma unroll
    for (int k = 0; k < RBFN; k++) { ewv[k] = e0[k]; ews[k] = e1[k]; ewd[k] = e2[k]; }
    float ebv = eb[f], ebs = eb[FD + f], ebd = eb[2 * FD + f];

    float accs = 0.f, accv0 = 0.f, accv1 = 0.f, accv2 = 0.f;
    int beg = row_ptr[n], end = row_ptr[n + 1];
    for (int j = beg; j < end; j++) {
        int e = edge_list[j];
        int dst = graph[2 * e + 1];
        float ce = cutb[e];
        const float* rb = rbf + (size_t)e * RBFN;
        float drv = ebv, drs = ebs, drd = ebd;
        #pragma unroll
        for (int k = 0; k < RBFN; k++) {
            float r = rb[k];
            drv += r * ewv[k]; drs += r * ews[k]; drd += r * ewd[k];
        }
        drv *= ce; drs *= ce; drd *= ce;
        const float* arow = a + (size_t)dst * F3;
        float rv = arow[f]          * drv;
        float rs = arow[FD + f]     * drs;
        float rd = arow[2 * FD + f] * drd;
        accs += rs;
        const float* vrow = v_in + (size_t)dst * F3;
        float sx = sense[3 * e + 0], sy = sense[3 * e + 1], sz = sense[3 * e + 2];
        accv0 += vrow[f]           * rv + sx * rd;
        accv1 += vrow[FD + f]      * rv + sy * rd;
        accv2 += vrow[2 * FD + f]  * rv + sz * rd;
    }
    int nb = n * FD + f;
    s_out[nb] = s_in[nb] + 2.f * accs;
    int vb = n * F3 + f;
    v_out[vb]          = v_in[vb]          + 2.f * accv0;
    v_out[vb + FD]     = v_in[vb + FD]     + 2.f * accv1;
    v_out[vb + 2 * FD] = v_in[vb + 2 * FD] + 2.f * accv2;
}

// ---------------------------------------------------------------- h build: [s, |Vv|]
__global__ __launch_bounds__(256) void build_h_kernel(const float* __restrict__ s_mid,
    const float* __restrict__ Vv, float* __restrict__ h)
{
    int idx = blockIdx.x * 256 + threadIdx.x;
    if (idx >= NN * FD) return;
    int n = idx >> 7, f = idx & 127;
    h[n * F2 + f] = s_mid[idx];
    float x0 = Vv[n * F3 + f];
    float x1 = Vv[n * F3 + FD + f];
    float x2 = Vv[n * F3 + 2 * FD + f];
    h[n * F2 + FD + f] = sqrtf(x0 * x0 + x1 * x1 + x2 * x2);
}

// ---------------------------------------------------------------- node update
__global__ __launch_bounds__(256) void update_kernel(const float* __restrict__ s_mid,
    const float* __restrict__ v_mid, const float* __restrict__ a2,
    const float* __restrict__ Uv, const float* __restrict__ Vv,
    float* __restrict__ s_out, float* __restrict__ v_out)
{
    int idx = blockIdx.x * 256 + threadIdx.x;
    if (idx >= NN * FD) return;
    int n = idx >> 7, f = idx & 127;
    int vb = n * F3 + f;
    float u0 = Uv[vb], u1 = Uv[vb + FD], u2 = Uv[vb + 2 * FD];
    float w0 = Vv[vb], w1 = Vv[vb + FD], w2 = Vv[vb + 2 * FD];
    float dot = u0 * w0 + u1 * w1 + u2 * w2;
    float avv = a2[n * F3 + f];
    float asv = a2[n * F3 + FD + f];
    float ass = a2[n * F3 + 2 * FD + f];
    s_out[idx] = s_mid[idx] + ass + asv * dot;
    v_out[vb]          = v_mid[vb]          + avv * u0;
    v_out[vb + FD]     = v_mid[vb + FD]     + avv * u1;
    v_out[vb + 2 * FD] = v_mid[vb + 2 * FD] + avv * u2;
}

// ---------------------------------------------------------------- final head + molecule reduce
__global__ __launch_bounds__(64) void zero_out_kernel(float* __restrict__ out)
{
    if (threadIdx.x < NMOL) out[threadIdx.x] = 0.f;
}

__global__ __launch_bounds__(256) void final_reduce_kernel(const float* __restrict__ t,
    const float* __restrict__ ow2, const float* __restrict__ ob2,
    const int* __restrict__ gidx, float* __restrict__ out)
{
    int gt = blockIdx.x * 256 + threadIdx.x;
    int n = gt >> 6;
    int lane = threadIdx.x & 63;
    if (n >= NN) return;
    float v = t[n * FD + lane] * ow2[lane] + t[n * FD + 64 + lane] * ow2[64 + lane];
    #pragma unroll
    for (int off = 32; off > 0; off >>= 1) v += __shfl_down(v, off);
    if (lane == 0) atomicAdd(&out[gidx[n]], v + ob2[0]);
}

// ---------------------------------------------------------------- launch
extern "C" void kernel_launch(void* const* d_in, const int* in_sizes, int n_in,
                              void* d_out, int out_size, void* d_ws, size_t ws_size,
                              hipStream_t stream)
{
    const int*   z     = (const int*)d_in[0];
    const int*   graph = (const int*)d_in[1];
    const float* dist  = (const float*)d_in[2];
    const float* sense = (const float*)d_in[3];
    const int*   gidx  = (const int*)d_in[4];
    const float* emb   = (const float*)d_in[5];
    const float* mw1   = (const float*)d_in[6];
    const float* mb1   = (const float*)d_in[7];
    const float* mw2   = (const float*)d_in[8];
    const float* mb2   = (const float*)d_in[9];
    const float* ew    = (const float*)d_in[10];
    const float* eb    = (const float*)d_in[11];
    const float* uw    = (const float*)d_in[12];
    const float* vw    = (const float*)d_in[13];
    const float* aw1   = (const float*)d_in[14];
    const float* ab1   = (const float*)d_in[15];
    const float* aw2   = (const float*)d_in[16];
    const float* ab2   = (const float*)d_in[17];
    const float* ow1   = (const float*)d_in[18];
    const float* ob1   = (const float*)d_in[19];
    const float* ow2   = (const float*)d_in[20];
    const float* ob2   = (const float*)d_in[21];
    float* out = (float*)d_out;

    // workspace carve-up
    float* W = (float*)d_ws;
    float* s_a    = W; W += (size_t)NN * FD;
    float* s_b    = W; W += (size_t)NN * FD;
    float* v_a    = W; W += (size_t)NN * F3;
    float* v_b    = W; W += (size_t)NN * F3;
    float* a_buf  = W; W += (size_t)NN * F3;   // aliased as h later in the iteration
    float* t_buf  = W; W += (size_t)NN * FD;
    float* a2_buf = W; W += (size_t)NN * F3;
    float* Uv     = W; W += (size_t)NN * F3;
    float* Vv     = W; W += (size_t)NN * F3;
    float* rbf    = W; W += (size_t)NE * RBFN;
    float* cutb   = W; W += (size_t)NE;
    int* ip = (int*)W;
    int* row_ptr   = ip; ip += NN + 1;
    int* cnt       = ip; ip += NN;
    int* cursor    = ip; ip += NN;
    int* edge_list = ip; ip += NE;
    float* h_buf = a_buf;

    const int TB = 256;
    dim3 b256(TB);

    // --- precompute ---
    embed_kernel<<<dim3((NN * FD + TB - 1) / TB), b256, 0, stream>>>(z, emb, s_a);
    zero_f_kernel<<<dim3((NN * F3 + TB - 1) / TB), b256, 0, stream>>>(v_a, NN * F3);
    rbf_kernel<<<dim3((NE + TB - 1) / TB), b256, 0, stream>>>(dist, rbf, cutb);
    zero_i_kernel<<<dim3((NN + TB - 1) / TB), b256, 0, stream>>>(cnt, NN);
    csr_count_kernel<<<dim3((NE + TB - 1) / TB), b256, 0, stream>>>(graph, cnt);
    csr_scan_kernel<<<dim3(1), dim3(1024), 0, stream>>>(cnt, row_ptr, cursor);
    csr_scatter_kernel<<<dim3((NE + TB - 1) / TB), b256, 0, stream>>>(graph, cursor, edge_list);

    dim3 gN2((NN + 63) / 64, FD / 64);         // M=N,  Nc=128
    dim3 gN6((NN + 63) / 64, F3 / 64);         // M=N,  Nc=384
    dim3 gV2((3 * NN + 63) / 64, FD / 64);     // M=3N, Nc=128

    for (int i = 0; i < NITER; i++) {
        // a = silu(s@mw1^T+mb1)@mw2^T+mb2
        gemm_mfma<true ><<<gN2, b256, 0, stream>>>(s_a, mw1 + (size_t)i * FD * FD, mb1 + (size_t)i * FD, t_buf, NN, FD, FD);
        gemm_mfma<false><<<gN6, b256, 0, stream>>>(t_buf, mw2 + (size_t)i * F3 * FD, mb2 + (size_t)i * F3, a_buf, NN, FD, F3);
        // message passing: s_b = s_a + 2*segsum(rs), v_b = v_a + 2*segsum(resv)
        edge_aggregate_kernel<<<dim3(NN), dim3(128), 0, stream>>>(
            graph, sense, rbf, cutb,
            ew + (size_t)i * F3 * RBFN, eb + (size_t)i * F3,
            a_buf, s_a, v_a, row_ptr, edge_list, s_b, v_b);
        // Uv, Vv
        gemm_mfma<false><<<gV2, b256, 0, stream>>>(v_b, uw + (size_t)i * FD * FD, nullptr, Uv, 3 * NN, FD, FD);
        gemm_mfma<false><<<gV2, b256, 0, stream>>>(v_b, vw + (size_t)i * FD * FD, nullptr, Vv, 3 * NN, FD, FD);
        // h = [s_b, |Vv|]
        build_h_kernel<<<dim3((NN * FD + TB - 1) / TB), b256, 0, stream>>>(s_b, Vv, h_buf);
        // a2 = silu(h@aw1^T+ab1)@aw2^T+ab2
        gemm_mfma<true ><<<gN2, b256, 0, stream>>>(h_buf, aw1 + (size_t)i * FD * F2, ab1 + (size_t)i * FD, t_buf, NN, F2, FD);
        gemm_mfma<false><<<gN6, b256, 0, stream>>>(t_buf, aw2 + (size_t)i * F3 * FD, ab2 + (size_t)i * F3, a2_buf, NN, FD, F3);
        // s_a, v_a <- updated state
        update_kernel<<<dim3((NN * FD + TB - 1) / TB), b256, 0, stream>>>(s_b, v_b, a2_buf, Uv, Vv, s_a, v_a);
    }

    // output head + molecule segment-sum
    gemm_mfma<true><<<gN2, b256, 0, stream>>>(s_a, ow1, ob1, t_buf, NN, FD, FD);
    zero_out_kernel<<<dim3(1), dim3(64), 0, stream>>>(out);
    final_reduce_kernel<<<dim3((NN * 64 + TB - 1) / TB), b256, 0, stream>>>(t_buf, ow2, ob2, gidx, out);
}

// Round 3
// 1096.694 us; speedup vs baseline: 1.6184x; 1.2970x over previous
//
#include <hip/hip_runtime.h>
#include <math.h>

// Problem constants
#define NN 20000
#define NE 320000
#define FD 128
#define RBFN 20
#define RC_ 5.0f
#define NITER 3
#define NMOL 64
#define F3 384
#define F2 256
#define PI_ 3.14159265358979323846f
#define KB 128
#define LPAD 8

typedef __attribute__((ext_vector_type(8))) short  bf16x8;
typedef __attribute__((ext_vector_type(4))) float  floatx4;
typedef unsigned short u16;

__device__ __forceinline__ u16 f2b(float x) {
    union { float f; unsigned int u; } v; v.f = x;
    unsigned int u = v.u;
    return (u16)((u + 0x7fffu + ((u >> 16) & 1u)) >> 16);   // RNE
}
__device__ __forceinline__ float b2f(u16 x) {
    union { unsigned int u; float f; } v; v.u = ((unsigned int)x) << 16;
    return v.f;
}

// ---------------------------------------------------------------- weight cvt (once per launch)
__global__ __launch_bounds__(256) void cvt_w_kernel(
    const float* s0, int n0, const float* s1, int n1, const float* s2, int n2,
    const float* s3, int n3, const float* s4, int n4, const float* s5, int n5,
    const float* s6, int n6, u16* __restrict__ dst)
{
    int idx = blockIdx.x * 256 + threadIdx.x;
    if (idx < n0) { dst[idx] = f2b(s0[idx]); return; } idx -= n0; dst += n0;
    if (idx < n1) { dst[idx] = f2b(s1[idx]); return; } idx -= n1; dst += n1;
    if (idx < n2) { dst[idx] = f2b(s2[idx]); return; } idx -= n2; dst += n2;
    if (idx < n3) { dst[idx] = f2b(s3[idx]); return; } idx -= n3; dst += n3;
    if (idx < n4) { dst[idx] = f2b(s4[idx]); return; } idx -= n4; dst += n4;
    if (idx < n5) { dst[idx] = f2b(s5[idx]); return; } idx -= n5; dst += n5;
    if (idx < n6) { dst[idx] = f2b(s6[idx]); }
}

// ---------------------------------------------------------------- elementwise
__global__ __launch_bounds__(256) void embed_kernel(const int* __restrict__ z,
    const float* __restrict__ emb, float* __restrict__ s, u16* __restrict__ sbf)
{
    int idx = blockIdx.x * 256 + threadIdx.x;
    if (idx >= NN * FD) return;
    int n = idx >> 7, f = idx & 127;
    float v = emb[z[n] * FD + f];
    s[idx] = v; sbf[idx] = f2b(v);
}

__global__ __launch_bounds__(256) void zero_f_kernel(float* __restrict__ p, int n)
{
    int idx = blockIdx.x * 256 + threadIdx.x;
    if (idx < n) p[idx] = 0.f;
}

__global__ __launch_bounds__(256) void zero_i_kernel(int* __restrict__ p, int n)
{
    int idx = blockIdx.x * 256 + threadIdx.x;
    if (idx < n) p[idx] = 0;
}

// ---------------------------------------------------------------- CSR build
__global__ __launch_bounds__(256) void csr_count_kernel(const int* __restrict__ graph,
    int* __restrict__ cnt)
{
    int e = blockIdx.x * 256 + threadIdx.x;
    if (e >= NE) return;
    atomicAdd(&cnt[graph[2 * e]], 1);
}

__global__ __launch_bounds__(1024) void csr_scan_kernel(const int* __restrict__ cnt,
    int* __restrict__ row_ptr, int* __restrict__ cursor)
{
    __shared__ int sd[1024];
    int tid = threadIdx.x;
    const int chunk = (NN + 1023) / 1024;
    int start = tid * chunk;
    int end = start + chunk; if (end > NN) end = NN;
    int sum = 0;
    for (int j = start; j < end; j++) sum += cnt[j];
    sd[tid] = sum;
    __syncthreads();
    for (int off = 1; off < 1024; off <<= 1) {
        int v = 0;
        if (tid >= off) v = sd[tid - off];
        __syncthreads();
        if (tid >= off) sd[tid] += v;
        __syncthreads();
    }
    int run = (tid == 0) ? 0 : sd[tid - 1];
    for (int j = start; j < end; j++) {
        row_ptr[j] = run;
        cursor[j]  = run;
        run += cnt[j];
    }
    if (tid == 0) row_ptr[NN] = NE;
}

__global__ __launch_bounds__(256) void csr_scatter_kernel(const int* __restrict__ graph,
    int* __restrict__ cursor, int* __restrict__ edge_list)
{
    int e = blockIdx.x * 256 + threadIdx.x;
    if (e >= NE) return;
    int p = atomicAdd(&cursor[graph[2 * e]], 1);
    edge_list[p] = e;
}

// Permuted edge streams in CSR order (loop-invariant): rbf/cut/sense/dst
__global__ __launch_bounds__(256) void edge_stream_kernel(
    const int* __restrict__ edge_list, const int* __restrict__ graph,
    const float* __restrict__ dist, const float* __restrict__ sense,
    float* __restrict__ rbf_p, float* __restrict__ cut_p,
    float* __restrict__ sense_p, int* __restrict__ dst_p)
{
    int j = blockIdx.x * 256 + threadIdx.x;
    if (j >= NE) return;
    int e = edge_list[j];
    float d = dist[e];
    float inv = 1.f / d;
    float base = PI_ * d / RC_;
    #pragma unroll
    for (int k = 0; k < RBFN; k++)
        rbf_p[(size_t)j * RBFN + k] = sinf((float)(k + 1) * base) * inv;
    cut_p[j] = 0.5f * (cosf(base) + 1.f) * (d < RC_ ? 1.f : 0.f);
    dst_p[j] = graph[2 * e + 1];
    sense_p[3 * j + 0] = sense[3 * e + 0];
    sense_p[3 * j + 1] = sense[3 * e + 1];
    sense_p[3 * j + 2] = sense[3 * e + 2];
}

// ---------------------------------------------------------------- bf16 MFMA GEMM
// C = act(A @ Wt^T + bias). A:(M,K) bf16, Wt:(Nc,K) bf16. Writes fp32 C and/or bf16 Cb.
template<bool SILU>
__global__ __launch_bounds__(256) void gemm_bf16(const u16* __restrict__ A,
    const u16* __restrict__ Wt, const float* __restrict__ bias,
    float* __restrict__ C, u16* __restrict__ Cb, int M, int K, int Nc)
{
    __shared__ u16 As[64][KB + LPAD];
    __shared__ u16 Bs[64][KB + LPAD];
    const int bm = blockIdx.x * 64;
    const int bn = blockIdx.y * 64;
    const int tid = threadIdx.x;
    const int r = tid >> 2;       // staging row 0..63
    const int q = tid & 3;        // 32-elem column quarter
    const int wave = tid >> 6;
    const int lane = tid & 63;
    const int wm = (wave >> 1) * 32;
    const int wn = (wave & 1) * 32;
    const int quad = lane >> 4;
    const int lr = lane & 15;

    floatx4 acc[2][2];
    #pragma unroll
    for (int i = 0; i < 2; i++)
        #pragma unroll
        for (int j = 0; j < 2; j++)
            acc[i][j] = (floatx4)0.f;

    for (int ko = 0; ko < K; ko += KB) {
        {
            int gm = bm + r;
            u16* dA = &As[r][q * 32];
            if (gm < M) {
                const u16* ap = A + (size_t)gm * K + ko + q * 32;
                #pragma unroll
                for (int x = 0; x < 32; x += 8)
                    *(bf16x8*)&dA[x] = *(const bf16x8*)(ap + x);
            } else {
                #pragma unroll
                for (int x = 0; x < 32; x += 8)
                    *(bf16x8*)&dA[x] = (bf16x8)0;
            }
        }
        {
            int gn = bn + r;   // Nc multiple of 64 -> no guard
            const u16* wp = Wt + (size_t)gn * K + ko + q * 32;
            u16* dB = &Bs[r][q * 32];
            #pragma unroll
            for (int x = 0; x < 32; x += 8)
                *(bf16x8*)&dB[x] = *(const bf16x8*)(wp + x);
        }
        __syncthreads();
        #pragma unroll
        for (int kk = 0; kk < KB; kk += 32) {
            bf16x8 a0 = *(const bf16x8*)&As[wm + lr     ][kk + quad * 8];
            bf16x8 a1 = *(const bf16x8*)&As[wm + 16 + lr][kk + quad * 8];
            bf16x8 b0 = *(const bf16x8*)&Bs[wn + lr     ][kk + quad * 8];
            bf16x8 b1 = *(const bf16x8*)&Bs[wn + 16 + lr][kk + quad * 8];
            acc[0][0] = __builtin_amdgcn_mfma_f32_16x16x32_bf16(a0, b0, acc[0][0], 0, 0, 0);
            acc[0][1] = __builtin_amdgcn_mfma_f32_16x16x32_bf16(a0, b1, acc[0][1], 0, 0, 0);
            acc[1][0] = __builtin_amdgcn_mfma_f32_16x16x32_bf16(a1, b0, acc[1][0], 0, 0, 0);
            acc[1][1] = __builtin_amdgcn_mfma_f32_16x16x32_bf16(a1, b1, acc[1][1], 0, 0, 0);
        }
        __syncthreads();
    }

    #pragma unroll
    for (int i = 0; i < 2; i++) {
        #pragma unroll
        for (int j = 0; j < 2; j++) {
            int gn = bn + wn + j * 16 + lr;
            float bb = bias ? bias[gn] : 0.f;
            #pragma unroll
            for (int rr = 0; rr < 4; rr++) {
                int gm = bm + wm + i * 16 + quad * 4 + rr;
                if (gm < M) {
                    float v = acc[i][j][rr] + bb;
                    if (SILU) v = v / (1.f + __expf(-v));
                    if (C)  C [(size_t)gm * Nc + gn] = v;
                    if (Cb) Cb[(size_t)gm * Nc + gn] = f2b(v);
                }
            }
        }
    }
}

// Dual GEMM: U = A@Wu^T, V = A@Wv^T (K=128, Nc=128), A staged once. bf16 outs.
__global__ __launch_bounds__(256) void gemm_uv(const u16* __restrict__ A,
    const u16* __restrict__ Wu, const u16* __restrict__ Wv,
    u16* __restrict__ U, u16* __restrict__ V, int M)
{
    __shared__ u16 As[64][KB + LPAD];
    __shared__ u16 Bu[64][KB + LPAD];
    __shared__ u16 Bv[64][KB + LPAD];
    const int bm = blockIdx.x * 64;
    const int bn = blockIdx.y * 64;
    const int tid = threadIdx.x;
    const int r = tid >> 2;
    const int q = tid & 3;
    const int wave = tid >> 6;
    const int lane = tid & 63;
    const int wm = (wave >> 1) * 32;
    const int wn = (wave & 1) * 32;
    const int quad = lane >> 4;
    const int lr = lane & 15;

    floatx4 au[2][2], av[2][2];
    #pragma unroll
    for (int i = 0; i < 2; i++)
        #pragma unroll
        for (int j = 0; j < 2; j++) { au[i][j] = (floatx4)0.f; av[i][j] = (floatx4)0.f; }

    {
        int gm = bm + r;
        u16* dA = &As[r][q * 32];
        if (gm < M) {
            const u16* ap = A + (size_t)gm * KB + q * 32;
            #pragma unroll
            for (int x = 0; x < 32; x += 8)
                *(bf16x8*)&dA[x] = *(const bf16x8*)(ap + x);
        } else {
            #pragma unroll
            for (int x = 0; x < 32; x += 8)
                *(bf16x8*)&dA[x] = (bf16x8)0;
        }
        int gn = bn + r;
        const u16* up = Wu + (size_t)gn * KB + q * 32;
        const u16* vp = Wv + (size_t)gn * KB + q * 32;
        u16* dU = &Bu[r][q * 32];
        u16* dV = &Bv[r][q * 32];
        #pragma unroll
        for (int x = 0; x < 32; x += 8) {
            *(bf16x8*)&dU[x] = *(const bf16x8*)(up + x);
            *(bf16x8*)&dV[x] = *(const bf16x8*)(vp + x);
        }
    }
    __syncthreads();
    #pragma unroll
    for (int kk = 0; kk < KB; kk += 32) {
        bf16x8 a0 = *(const bf16x8*)&As[wm + lr     ][kk + quad * 8];
        bf16x8 a1 = *(const bf16x8*)&As[wm + 16 + lr][kk + quad * 8];
        bf16x8 u0 = *(const bf16x8*)&Bu[wn + lr     ][kk + quad * 8];
        bf16x8 u1 = *(const bf16x8*)&Bu[wn + 16 + lr][kk + quad * 8];
        bf16x8 v0 = *(const bf16x8*)&Bv[wn + lr     ][kk + quad * 8];
        bf16x8 v1 = *(const bf16x8*)&Bv[wn + 16 + lr][kk + quad * 8];
        au[0][0] = __builtin_amdgcn_mfma_f32_16x16x32_bf16(a0, u0, au[0][0], 0, 0, 0);
        au[0][1] = __builtin_amdgcn_mfma_f32_16x16x32_bf16(a0, u1, au[0][1], 0, 0, 0);
        au[1][0] = __builtin_amdgcn_mfma_f32_16x16x32_bf16(a1, u0, au[1][0], 0, 0, 0);
        au[1][1] = __builtin_amdgcn_mfma_f32_16x16x32_bf16(a1, u1, au[1][1], 0, 0, 0);
        av[0][0] = __builtin_amdgcn_mfma_f32_16x16x32_bf16(a0, v0, av[0][0], 0, 0, 0);
        av[0][1] = __builtin_amdgcn_mfma_f32_16x16x32_bf16(a0, v1, av[0][1], 0, 0, 0);
        av[1][0] = __builtin_amdgcn_mfma_f32_16x16x32_bf16(a1, v0, av[1][0], 0, 0, 0);
        av[1][1] = __builtin_amdgcn_mfma_f32_16x16x32_bf16(a1, v1, av[1][1], 0, 0, 0);
    }
    #pragma unroll
    for (int i = 0; i < 2; i++) {
        #pragma unroll
        for (int j = 0; j < 2; j++) {
            int gn = bn + wn + j * 16 + lr;
            #pragma unroll
            for (int rr = 0; rr < 4; rr++) {
                int gm = bm + wm + i * 16 + quad * 4 + rr;
                if (gm < M) {
                    U[(size_t)gm * FD + gn] = f2b(au[i][j][rr]);
                    V[(size_t)gm * FD + gn] = f2b(av[i][j][rr]);
                }
            }
        }
    }
}

// ---------------------------------------------------------------- edge aggregate (CSR streams, bf16 gathers)
__global__ __launch_bounds__(128) void edge_aggregate2(
    const float* __restrict__ rbf_p, const float* __restrict__ cut_p,
    const float* __restrict__ sense_p, const int* __restrict__ dst_p,
    const float* __restrict__ ew, const float* __restrict__ eb,
    const u16* __restrict__ a_bf, const float* __restrict__ s_in,
    const float* __restrict__ v_in, const u16* __restrict__ v_bf,
    const int* __restrict__ row_ptr,
    float* __restrict__ s_out, u16* __restrict__ s_obf,
    float* __restrict__ v_out, u16* __restrict__ v_obf)
{
    int n = blockIdx.x;
    int f = threadIdx.x;
    float ewv[RBFN], ews[RBFN], ewd[RBFN];
    const float* e0 = ew + (size_t)f * RBFN;
    const float* e1 = ew + (size_t)(FD + f) * RBFN;
    const float* e2 = ew + (size_t)(2 * FD + f) * RBFN;
    #pragma unroll
    for (int k = 0; k < RBFN; k++) { ewv[k] = e0[k]; ews[k] = e1[k]; ewd[k] = e2[k]; }
    float ebv = eb[f], ebs = eb[FD + f], ebd = eb[2 * FD + f];

    float accs = 0.f, accv0 = 0.f, accv1 = 0.f, accv2 = 0.f;
    int beg = row_ptr[n], end = row_ptr[n + 1];
    for (int j = beg; j < end; j++) {
        int dst = dst_p[j];
        float ce = cut_p[j];
        const float* rb = rbf_p + (size_t)j * RBFN;
        float drv = ebv, drs = ebs, drd = ebd;
        #pragma unroll
        for (int k = 0; k < RBFN; k++) {
            float r = rb[k];
            drv += r * ewv[k]; drs += r * ews[k]; drd += r * ewd[k];
        }
        drv *= ce; drs *= ce; drd *= ce;
        const u16* ar = a_bf + (size_t)dst * F3;
        float rv = b2f(ar[f])          * drv;
        float rs = b2f(ar[FD + f])     * drs;
        float rd = b2f(ar[2 * FD + f]) * drd;
        accs += rs;
        const u16* vr = v_bf + (size_t)dst * F3;
        float sx = sense_p[3 * j + 0], sy = sense_p[3 * j + 1], sz = sense_p[3 * j + 2];
        accv0 += b2f(vr[f])          * rv + sx * rd;
        accv1 += b2f(vr[FD + f])     * rv + sy * rd;
        accv2 += b2f(vr[2 * FD + f]) * rv + sz * rd;
    }
    int nb = n * FD + f;
    float so = s_in[nb] + 2.f * accs;
    s_out[nb] = so; s_obf[nb] = f2b(so);
    int vb = n * F3 + f;
    float w0 = v_in[vb]           + 2.f * accv0;
    float w1 = v_in[vb + FD]      + 2.f * accv1;
    float w2 = v_in[vb + 2 * FD]  + 2.f * accv2;
    v_out[vb]          = w0; v_obf[vb]          = f2b(w0);
    v_out[vb + FD]     = w1; v_obf[vb + FD]     = f2b(w1);
    v_out[vb + 2 * FD] = w2; v_obf[vb + 2 * FD] = f2b(w2);
}

// ---------------------------------------------------------------- h build (bf16): [s, |Vv|]
__global__ __launch_bounds__(256) void build_h_kernel(const u16* __restrict__ sbf,
    const u16* __restrict__ Vv, u16* __restrict__ h)
{
    int idx = blockIdx.x * 256 + threadIdx.x;
    if (idx >= NN * FD) return;
    int n = idx >> 7, f = idx & 127;
    h[n * F2 + f] = sbf[idx];
    float x0 = b2f(Vv[n * F3 + f]);
    float x1 = b2f(Vv[n * F3 + FD + f]);
    float x2 = b2f(Vv[n * F3 + 2 * FD + f]);
    h[n * F2 + FD + f] = f2b(sqrtf(x0 * x0 + x1 * x1 + x2 * x2));
}

// ---------------------------------------------------------------- node update
__global__ __launch_bounds__(256) void update_kernel(const float* __restrict__ s_mid,
    const float* __restrict__ v_mid, const u16* __restrict__ a2,
    const u16* __restrict__ Uv, const u16* __restrict__ Vv,
    float* __restrict__ s_out, u16* __restrict__ s_obf,
    float* __restrict__ v_out, u16* __restrict__ v_obf)
{
    int idx = blockIdx.x * 256 + threadIdx.x;
    if (idx >= NN * FD) return;
    int n = idx >> 7, f = idx & 127;
    int vb = n * F3 + f;
    float u0 = b2f(Uv[vb]), u1 = b2f(Uv[vb + FD]), u2 = b2f(Uv[vb + 2 * FD]);
    float w0 = b2f(Vv[vb]), w1 = b2f(Vv[vb + FD]), w2 = b2f(Vv[vb + 2 * FD]);
    float dot = u0 * w0 + u1 * w1 + u2 * w2;
    float avv = b2f(a2[n * F3 + f]);
    float asv = b2f(a2[n * F3 + FD + f]);
    float ass = b2f(a2[n * F3 + 2 * FD + f]);
    float so = s_mid[idx] + ass + asv * dot;
    s_out[idx] = so; s_obf[idx] = f2b(so);
    float y0 = v_mid[vb]          + avv * u0;
    float y1 = v_mid[vb + FD]     + avv * u1;
    float y2 = v_mid[vb + 2 * FD] + avv * u2;
    v_out[vb]          = y0; v_obf[vb]          = f2b(y0);
    v_out[vb + FD]     = y1; v_obf[vb + FD]     = f2b(y1);
    v_out[vb + 2 * FD] = y2; v_obf[vb + 2 * FD] = f2b(y2);
}

// ---------------------------------------------------------------- final head + molecule reduce
__global__ __launch_bounds__(64) void zero_out_kernel(float* __restrict__ out)
{
    if (threadIdx.x < NMOL) out[threadIdx.x] = 0.f;
}

__global__ __launch_bounds__(256) void final_reduce_kernel(const float* __restrict__ t,
    const float* __restrict__ ow2, const float* __restrict__ ob2,
    const int* __restrict__ gidx, float* __restrict__ out)
{
    int gt = blockIdx.x * 256 + threadIdx.x;
    int n = gt >> 6;
    int lane = threadIdx.x & 63;
    if (n >= NN) return;
    float v = t[n * FD + lane] * ow2[lane] + t[n * FD + 64 + lane] * ow2[64 + lane];
    #pragma unroll
    for (int off = 32; off > 0; off >>= 1) v += __shfl_down(v, off);
    if (lane == 0) atomicAdd(&out[gidx[n]], v + ob2[0]);
}

// ---------------------------------------------------------------- launch
extern "C" void kernel_launch(void* const* d_in, const int* in_sizes, int n_in,
                              void* d_out, int out_size, void* d_ws, size_t ws_size,
                              hipStream_t stream)
{
    const int*   z     = (const int*)d_in[0];
    const int*   graph = (const int*)d_in[1];
    const float* dist  = (const float*)d_in[2];
    const float* sense = (const float*)d_in[3];
    const int*   gidx  = (const int*)d_in[4];
    const float* emb   = (const float*)d_in[5];
    const float* mw1   = (const float*)d_in[6];
    const float* mb1   = (const float*)d_in[7];
    const float* mw2   = (const float*)d_in[8];
    const float* mb2   = (const float*)d_in[9];
    const float* ew    = (const float*)d_in[10];
    const float* eb    = (const float*)d_in[11];
    const float* uw    = (const float*)d_in[12];
    const float* vw    = (const float*)d_in[13];
    const float* aw1   = (const float*)d_in[14];
    const float* ab1   = (const float*)d_in[15];
    const float* aw2   = (const float*)d_in[16];
    const float* ab2   = (const float*)d_in[17];
    const float* ow1   = (const float*)d_in[18];
    const float* ob1   = (const float*)d_in[19];
    const float* ow2   = (const float*)d_in[20];
    const float* ob2   = (const float*)d_in[21];
    float* out = (float*)d_out;

    // ---- workspace carve-up (~235 MB) ----
    float* W = (float*)d_ws;
    float* s_a    = W; W += (size_t)NN * FD;
    float* s_b    = W; W += (size_t)NN * FD;
    float* v_a    = W; W += (size_t)NN * F3;
    float* v_b    = W; W += (size_t)NN * F3;
    float* rbf_p  = W; W += (size_t)NE * RBFN;
    float* cut_p  = W; W += (size_t)NE;
    float* sns_p  = W; W += (size_t)NE * 3;
    float* tfin   = W; W += (size_t)NN * FD;
    u16* U = (u16*)W;
    u16* sbf_a = U; U += (size_t)NN * FD;
    u16* sbf_b = U; U += (size_t)NN * FD;
    u16* vbf_a = U; U += (size_t)NN * F3;
    u16* vbf_b = U; U += (size_t)NN * F3;
    u16* a_bf  = U; U += (size_t)NN * F3;   // h_bf aliases (NN*F2 <= NN*F3)
    u16* t_bf  = U; U += (size_t)NN * FD;
    u16* a2_bf = U; U += (size_t)NN * F3;
    u16* Uv_bf = U; U += (size_t)NN * F3;
    u16* Vv_bf = U; U += (size_t)NN * F3;
    u16* wb    = U; U += 557056;
    int* ip = (int*)U;
    int* row_ptr   = ip; ip += NN + 1;
    int* cnt       = ip; ip += NN;
    int* cursor    = ip; ip += NN;
    int* edge_list = ip; ip += NE;
    int* dst_p     = ip; ip += NE;
    u16* h_bf = a_bf;

    // bf16 weight table offsets
    u16* wb_mw1 = wb;            // 3*128*128
    u16* wb_mw2 = wb + 49152;    // 3*384*128
    u16* wb_uw  = wb + 196608;   // 3*128*128
    u16* wb_vw  = wb + 245760;   // 3*128*128
    u16* wb_aw1 = wb + 294912;   // 3*128*256
    u16* wb_aw2 = wb + 393216;   // 3*384*128
    u16* wb_ow1 = wb + 540672;   // 128*128
    const int WTOT = 557056;

    const int TB = 256;
    dim3 b256(TB);

    // --- precompute ---
    cvt_w_kernel<<<dim3((WTOT + TB - 1) / TB), b256, 0, stream>>>(
        mw1, 49152, mw2, 147456, uw, 49152, vw, 49152, aw1, 98304, aw2, 147456,
        ow1, 16384, wb);
    embed_kernel<<<dim3((NN * FD + TB - 1) / TB), b256, 0, stream>>>(z, emb, s_a, sbf_a);
    zero_f_kernel<<<dim3((NN * F3 + TB - 1) / TB), b256, 0, stream>>>(v_a, NN * F3);
    zero_i_kernel<<<dim3((NN * F3 / 2 + TB - 1) / TB), b256, 0, stream>>>((int*)vbf_a, NN * F3 / 2);
    zero_i_kernel<<<dim3((NN + TB - 1) / TB), b256, 0, stream>>>(cnt, NN);
    csr_count_kernel<<<dim3((NE + TB - 1) / TB), b256, 0, stream>>>(graph, cnt);
    csr_scan_kernel<<<dim3(1), dim3(1024), 0, stream>>>(cnt, row_ptr, cursor);
    csr_scatter_kernel<<<dim3((NE + TB - 1) / TB), b256, 0, stream>>>(graph, cursor, edge_list);
    edge_stream_kernel<<<dim3((NE + TB - 1) / TB), b256, 0, stream>>>(
        edge_list, graph, dist, sense, rbf_p, cut_p, sns_p, dst_p);

    dim3 gN2((NN + 63) / 64, FD / 64);         // Nc=128
    dim3 gN6((NN + 63) / 64, F3 / 64);         // Nc=384
    dim3 gV2((3 * NN + 63) / 64, FD / 64);     // M=3N, Nc=128

    for (int i = 0; i < NITER; i++) {
        gemm_bf16<true ><<<gN2, b256, 0, stream>>>(sbf_a, wb_mw1 + (size_t)i * FD * FD,
            mb1 + (size_t)i * FD, nullptr, t_bf, NN, FD, FD);
        gemm_bf16<false><<<gN6, b256, 0, stream>>>(t_bf, wb_mw2 + (size_t)i * F3 * FD,
            mb2 + (size_t)i * F3, nullptr, a_bf, NN, FD, F3);
        edge_aggregate2<<<dim3(NN), dim3(128), 0, stream>>>(
            rbf_p, cut_p, sns_p, dst_p,
            ew + (size_t)i * F3 * RBFN, eb + (size_t)i * F3,
            a_bf, s_a, v_a, vbf_a, row_ptr, s_b, sbf_b, v_b, vbf_b);
        gemm_uv<<<gV2, b256, 0, stream>>>(vbf_b, wb_uw + (size_t)i * FD * FD,
            wb_vw + (size_t)i * FD * FD, Uv_bf, Vv_bf, 3 * NN);
        build_h_kernel<<<dim3((NN * FD + TB - 1) / TB), b256, 0, stream>>>(sbf_b, Vv_bf, h_bf);
        gemm_bf16<true ><<<gN2, b256, 0, stream>>>(h_bf, wb_aw1 + (size_t)i * FD * F2,
            ab1 + (size_t)i * FD, nullptr, t_bf, NN, F2, FD);
        gemm_bf16<false><<<gN6, b256, 0, stream>>>(t_bf, wb_aw2 + (size_t)i * F3 * FD,
            ab2 + (size_t)i * F3, nullptr, a2_bf, NN, FD, F3);
        update_kernel<<<dim3((NN * FD + TB - 1) / TB), b256, 0, stream>>>(
            s_b, v_b, a2_bf, Uv_bf, Vv_bf, s_a, sbf_a, v_a, vbf_a);
    }

    gemm_bf16<true><<<gN2, b256, 0, stream>>>(sbf_a, wb_ow1, ob1, tfin, nullptr, NN, FD, FD);
    zero_out_kernel<<<dim3(1), dim3(64), 0, stream>>>(out);
    final_reduce_kernel<<<dim3((NN * 64 + TB - 1) / TB), b256, 0, stream>>>(tfin, ow2, ob2, gidx, out);
}